// Round 14
// baseline (27.389 us; speedup 1.0000x reference)
//
#include <hip/hip_runtime.h>

#define B_ 2
#define L_ 256
#define H_ 256
#define A_ 32
#define P_ 64
#define PSTR 76    // posT LDS row stride (floats)
#define TSTR 516   // out-tile LDS row stride (floats): 8*64 + 4

typedef __bf16 bf16x8 __attribute__((ext_vector_type(8)));
typedef float  f32x4  __attribute__((ext_vector_type(4)));

// k1: 256 blocks = 64 row-groups (8 rows) x 4 p-groups (16 p).
// h-phase (k1a-proven shuffle form, x via L1-broadcast GLOBAL loads, in_w in VGPRs,
//   zero DS): thread (jj,a,q) does a 64-length quarter-dot per row-pair pass (4 passes).
// g-phase (MFMA): for fixed a, g[r][p] = sum_c h[r][c] W[p][a][c] is 16x16x32
//   (M=r rows 0..7 real + 8 zero-pad, N=p, K=c). A-frag = bf16 h tile (LDS, 1KB);
//   B-frag = out_w rounded bf16 in-flight. Wave w covers a = w*8..w*8+7 -> lane
//   collects 8 a-values per D-row -> one bf16x8 store = k2's gb[r][p][a] layout.
__global__ __launch_bounds__(256) void k1_proj(
    const float* __restrict__ x,     // [B,L,H]
    const float* __restrict__ in_w,  // [A,H]
    const float* __restrict__ in_b,  // [A]
    const float* __restrict__ out_w, // [P, A*A]
    __bf16* __restrict__ gb,         // [B*L][P][A] bf16
    __bf16* __restrict__ hb)         // [B*L][A]   bf16
{
    __shared__ __align__(16) __bf16 hfl[16][32];   // rows 8..15 zero-pad

    const int t = threadIdx.x;
    const int rowg = blockIdx.x >> 2;   // 0..63
    const int pg   = blockIdx.x & 3;    // p-group
    const int r0 = rowg * 8;
    const int p0 = pg * 16;

    // zero pad rows 8..15 (elems 256..511 -> uint idx 128..255)
    if (t < 128) ((unsigned int*)hfl)[128 + t] = 0u;

    // ---- h-phase ----
    {
        const int jj = t >> 7;          // row-pair member 0..1
        const int rem = t & 127;
        const int a = rem >> 2;         // 0..31
        const int q = rem & 3;          // quarter
        float4 wq[16];
        const float4* wr = (const float4*)(in_w + (size_t)a * H_ + q * 64);
        #pragma unroll
        for (int m = 0; m < 16; ++m) wq[m] = wr[m];
        const float bia = in_b[a];

        #pragma unroll
        for (int s = 0; s < 4; ++s) {
            const int row = r0 + 2 * s + jj;
            const float4* xv = (const float4*)(x + (size_t)row * H_ + q * 64);
            float sum = 0.f;
            #pragma unroll
            for (int m = 0; m < 16; ++m) {
                const float4 w = wq[m];
                const float4 xx = xv[m];     // 4 distinct addrs/wave -> L1 broadcast
                sum += w.x * xx.x + w.y * xx.y + w.z * xx.z + w.w * xx.w;
            }
            sum += __shfl_xor(sum, 1);
            sum += __shfl_xor(sum, 2);
            if (q == 0) {
                const float hv = sum + bia;
                hfl[2 * s + jj][a] = (__bf16)hv;
                if (pg == 0) hb[(size_t)row * A_ + a] = (__bf16)hv;
            }
        }
    }
    __syncthreads();

    // ---- g-phase (MFMA) ----
    const int lane = t & 63;
    const int w = t >> 6;              // wave -> a = w*8 .. +7
    const int l15 = lane & 15;
    const int hi = lane >> 4;          // k-chunk for frags; D rows hi*4+reg

    const bf16x8 hfrag = *(const bf16x8*)&hfl[l15][hi * 8];
    const f32x4 zero = {0.f, 0.f, 0.f, 0.f};

    float accs[4][8];                  // [reg][a-local]
    #pragma unroll
    for (int al = 0; al < 8; ++al) {
        const int a = w * 8 + al;
        const float* wp = out_w + (size_t)(p0 + l15) * (A_ * A_) + a * A_ + hi * 8;
        const float4 w0 = *(const float4*)wp;
        const float4 w1 = *(const float4*)(wp + 4);
        bf16x8 wf;
        wf[0] = (__bf16)w0.x; wf[1] = (__bf16)w0.y; wf[2] = (__bf16)w0.z; wf[3] = (__bf16)w0.w;
        wf[4] = (__bf16)w1.x; wf[5] = (__bf16)w1.y; wf[6] = (__bf16)w1.z; wf[7] = (__bf16)w1.w;
        const f32x4 d = __builtin_amdgcn_mfma_f32_16x16x32_bf16(hfrag, wf, zero, 0, 0, 0);
        accs[0][al] = d[0]; accs[1][al] = d[1]; accs[2][al] = d[2]; accs[3][al] = d[3];
    }

    if (hi < 2) {                      // D rows 0..7 are real
        #pragma unroll
        for (int reg = 0; reg < 4; ++reg) {
            const int row = r0 + hi * 4 + reg;
            bf16x8 v;
            #pragma unroll
            for (int e = 0; e < 8; ++e) v[e] = (__bf16)accs[reg][e];
            *(bf16x8*)(gb + ((size_t)row * P_ + p0 + l15) * A_ + w * 8) = v;
        }
    }
}

// k2: verbatim R9 measured-best. out[b,i,j,p] = sum_a g[j,a,p] h[i,a] via
// mfma(A=g, B=h): D[m=p][n=i]; 16i x 8j x 64p tiles; LDS-staged fused epilogue,
// linear NT readout.
__global__ __launch_bounds__(256) void k2_mfma(
    const __bf16* __restrict__ gb,   // [B*L][P][A]
    const __bf16* __restrict__ hb,   // [B*L][A]
    const float* __restrict__ out_b, // [P]
    const float* __restrict__ pos_w, // [P,17]
    const float* __restrict__ pos_b, // [P]
    float* __restrict__ out)         // [B,L,L,P]
{
    __shared__ float posT[17 * PSTR];
    __shared__ float tile[16][TSTR];
    const int t = threadIdx.x;

    for (int e = t; e < 17 * P_; e += 256) {
        const int d = e >> 6, p = e & 63;
        posT[d * PSTR + p] = pos_w[p * 17 + d] + pos_b[p] + out_b[p];
    }
    __syncthreads();

    const int lane = t & 63;
    const int w = t >> 6;            // wave 0..3
    const int j0 = blockIdx.x * 8;
    const int i0 = blockIdx.y * 16;
    const int b = blockIdx.z;

    const int l15 = lane & 15;
    const int hi = lane >> 4;        // 0..3
    const int i = i0 + l15;
    const int p_r0 = hi * 4;

    const bf16x8 hfrag = *(const bf16x8*)(hb + ((size_t)(b * L_ + i)) * A_ + hi * 8);
    const f32x4 zero = {0.f, 0.f, 0.f, 0.f};

    #pragma unroll
    for (int tj = 0; tj < 2; ++tj) {
        const int jl = w * 2 + tj;   // local j 0..7
        const int j = j0 + jl;
        const __bf16* gr = gb + ((size_t)(b * L_ + j)) * (P_ * A_);

        bf16x8 gfrag[4];
        #pragma unroll
        for (int pgi = 0; pgi < 4; ++pgi)
            gfrag[pgi] = *(const bf16x8*)(gr + (pgi * 16 + l15) * A_ + hi * 8);

        f32x4 acc[4];
        #pragma unroll
        for (int pgi = 0; pgi < 4; ++pgi)
            acc[pgi] = __builtin_amdgcn_mfma_f32_16x16x32_bf16(gfrag[pgi], hfrag, zero, 0, 0, 0);

        int d = i - j;
        d = d < -8 ? -8 : (d > 8 ? 8 : d);
        d += 8;

        #pragma unroll
        for (int pgi = 0; pgi < 4; ++pgi) {
            const f32x4 pe = *(const f32x4*)(posT + d * PSTR + pgi * 16 + p_r0);
            *(f32x4*)&tile[l15][jl * 64 + pgi * 16 + p_r0] = acc[pgi] + pe;
        }
    }
    __syncthreads();

    const int ir = t >> 4;           // 0..15
    const int c  = t & 15;           // 0..15
    float* orow = out + (((size_t)(b * L_ + i0 + ir)) * L_ + j0) * P_;
    #pragma unroll
    for (int m = 0; m < 8; ++m) {
        const int f4 = m * 16 + c;
        const f32x4 v = *(const f32x4*)&tile[ir][f4 * 4];
        __builtin_nontemporal_store(v, (f32x4*)(orow + f4 * 4));
    }
}

extern "C" void kernel_launch(void* const* d_in, const int* in_sizes, int n_in,
                              void* d_out, int out_size, void* d_ws, size_t ws_size,
                              hipStream_t stream) {
    const float* x     = (const float*)d_in[0];
    const float* in_w  = (const float*)d_in[1];
    const float* in_b  = (const float*)d_in[2];
    const float* out_w = (const float*)d_in[3];
    const float* out_b = (const float*)d_in[4];
    const float* pos_w = (const float*)d_in[5];
    const float* pos_b = (const float*)d_in[6];
    float* out = (float*)d_out;

    __bf16* gb = (__bf16*)d_ws;                                   // 2 MB
    __bf16* hb = gb + (size_t)B_ * L_ * P_ * A_;                  // +32 KB

    k1_proj<<<dim3(256), 256, 0, stream>>>(x, in_w, in_b, out_w, gb, hb);
    k2_mfma<<<dim3(L_ / 8, L_ / 16, B_), 256, 0, stream>>>(gb, hb, out_b, pos_w, pos_b, out);
}

// Round 15
// 22.761 us; speedup vs baseline: 1.2034x; 1.2034x over previous
//
#include <hip/hip_runtime.h>

#define B_ 2
#define L_ 256
#define H_ 256
#define A_ 32
#define P_ 64
#define PSTR 76    // posT LDS row stride (floats)
#define TSTR 516   // out-tile LDS row stride (floats): 8*64 + 4
#define XSTR 260   // x LDS row stride (floats)

typedef __bf16 bf16x8 __attribute__((ext_vector_type(8)));
typedef float  f32x4  __attribute__((ext_vector_type(4)));

// k1 (R13's version, now de-confounded): 512 blocks = 64 row-groups x 8 p-octets.
// h-phase: in_w quarters in VGPRs (L2-resident global), x via 2-address LDS
//   broadcast; q-partials reduced through LDS (fixed order).
// g-phase: R9-identical broadcast form.
__global__ __launch_bounds__(256) void k1_proj(
    const float* __restrict__ x,     // [B,L,H]
    const float* __restrict__ in_w,  // [A,H]
    const float* __restrict__ in_b,  // [A]
    const float* __restrict__ out_w, // [P, A*A]
    __bf16* __restrict__ gb,         // [B*L][P][A] bf16
    __bf16* __restrict__ hb)         // [B*L][A]   bf16
{
    __shared__ float xs[8][XSTR];
    __shared__ float hp[4][8][33];   // q-partials
    __shared__ float hl[8][36];      // reduced h rows (f32)

    const int t = threadIdx.x;
    const int rowg = blockIdx.x >> 3;     // 0..63
    const int pe   = blockIdx.x & 7;      // p-octet
    const int r0 = rowg * 8;

    // stage x: 8 rows x 64 f4
    #pragma unroll
    for (int u = t; u < 512; u += 256) {
        const int row = u >> 6, c4 = u & 63;
        *(float4*)&xs[row][c4 * 4] = ((const float4*)(x + (size_t)(r0 + row) * H_))[c4];
    }
    __syncthreads();

    // h-phase: thread (a = t&31, r4 = (t>>5)&1, q = t>>6)
    {
        const int a  = t & 31;
        const int r4 = (t >> 5) & 1;      // rows r4*4 .. +3
        const int q  = t >> 6;            // quarter 0..3 (one q per wave)
        float4 wq[16];
        const float4* wr = (const float4*)(in_w + (size_t)a * H_ + q * 64);
        #pragma unroll
        for (int m = 0; m < 16; ++m) wq[m] = wr[m];

        float s0 = 0.f, s1 = 0.f, s2 = 0.f, s3 = 0.f;
        #pragma unroll
        for (int m = 0; m < 16; ++m) {
            const float4 w = wq[m];
            const float4 x0 = *(const float4*)&xs[r4 * 4 + 0][q * 64 + m * 4];
            const float4 x1 = *(const float4*)&xs[r4 * 4 + 1][q * 64 + m * 4];
            const float4 x2 = *(const float4*)&xs[r4 * 4 + 2][q * 64 + m * 4];
            const float4 x3 = *(const float4*)&xs[r4 * 4 + 3][q * 64 + m * 4];
            s0 += w.x * x0.x + w.y * x0.y + w.z * x0.z + w.w * x0.w;
            s1 += w.x * x1.x + w.y * x1.y + w.z * x1.z + w.w * x1.w;
            s2 += w.x * x2.x + w.y * x2.y + w.z * x2.z + w.w * x2.w;
            s3 += w.x * x3.x + w.y * x3.y + w.z * x3.z + w.w * x3.w;
        }
        hp[q][r4 * 4 + 0][a] = s0;
        hp[q][r4 * 4 + 1][a] = s1;
        hp[q][r4 * 4 + 2][a] = s2;
        hp[q][r4 * 4 + 3][a] = s3;
    }
    __syncthreads();

    // reduce q-partials: thread (row = t>>5, a = t&31)
    {
        const int row = t >> 5, a = t & 31;
        const float hv = ((hp[0][row][a] + hp[1][row][a]) +
                          (hp[2][row][a] + hp[3][row][a])) + in_b[a];
        hl[row][a] = hv;
        if (pe == 0) hb[(size_t)(r0 + row) * A_ + a] = (__bf16)hv;
    }
    __syncthreads();

    // g-phase (R9-identical): thread owns p = pe*8 + (t>>5), a = t&31
    {
        const int p = pe * 8 + (t >> 5);
        const int a = t & 31;
        const float4* wrow = (const float4*)(out_w + (size_t)p * (A_ * A_) + a * A_);
        float4 w[8];
        #pragma unroll
        for (int m = 0; m < 8; ++m) w[m] = wrow[m];
        float sac[8];
        #pragma unroll
        for (int jj = 0; jj < 8; ++jj) {
            float s = 0.f;
            #pragma unroll
            for (int m = 0; m < 8; ++m) {
                const float4 h4 = *(const float4*)&hl[jj][m * 4];   // uniform -> broadcast
                s += w[m].x * h4.x + w[m].y * h4.y + w[m].z * h4.z + w[m].w * h4.w;
            }
            sac[jj] = s;
        }
        #pragma unroll
        for (int jj = 0; jj < 8; ++jj)
            gb[((size_t)(r0 + jj) * P_ + p) * A_ + a] = (__bf16)sac[jj];
    }
}

// k2: VERBATIM R9 measured-best (1024 blocks). out[b,i,j,p] = sum_a g[j,a,p] h[i,a]
// via mfma(A=g, B=h): D[m=p][n=i]; 16i x 8j x 64p tiles; LDS-staged fused epilogue,
// linear NT readout.
__global__ __launch_bounds__(256) void k2_mfma(
    const __bf16* __restrict__ gb,   // [B*L][P][A]
    const __bf16* __restrict__ hb,   // [B*L][A]
    const float* __restrict__ out_b, // [P]
    const float* __restrict__ pos_w, // [P,17]
    const float* __restrict__ pos_b, // [P]
    float* __restrict__ out)         // [B,L,L,P]
{
    __shared__ float posT[17 * PSTR];
    __shared__ float tile[16][TSTR];
    const int t = threadIdx.x;

    for (int e = t; e < 17 * P_; e += 256) {
        const int d = e >> 6, p = e & 63;
        posT[d * PSTR + p] = pos_w[p * 17 + d] + pos_b[p] + out_b[p];
    }
    __syncthreads();

    const int lane = t & 63;
    const int w = t >> 6;            // wave 0..3
    const int j0 = blockIdx.x * 8;
    const int i0 = blockIdx.y * 16;
    const int b = blockIdx.z;

    const int l15 = lane & 15;
    const int hi = lane >> 4;        // 0..3
    const int i = i0 + l15;
    const int p_r0 = hi * 4;

    const bf16x8 hfrag = *(const bf16x8*)(hb + ((size_t)(b * L_ + i)) * A_ + hi * 8);
    const f32x4 zero = {0.f, 0.f, 0.f, 0.f};

    #pragma unroll
    for (int tj = 0; tj < 2; ++tj) {
        const int jl = w * 2 + tj;   // local j 0..7
        const int j = j0 + jl;
        const __bf16* gr = gb + ((size_t)(b * L_ + j)) * (P_ * A_);

        bf16x8 gfrag[4];
        #pragma unroll
        for (int pg = 0; pg < 4; ++pg)
            gfrag[pg] = *(const bf16x8*)(gr + (pg * 16 + l15) * A_ + hi * 8);

        f32x4 acc[4];
        #pragma unroll
        for (int pg = 0; pg < 4; ++pg)
            acc[pg] = __builtin_amdgcn_mfma_f32_16x16x32_bf16(gfrag[pg], hfrag, zero, 0, 0, 0);

        int d = i - j;
        d = d < -8 ? -8 : (d > 8 ? 8 : d);
        d += 8;

        #pragma unroll
        for (int pg = 0; pg < 4; ++pg) {
            const f32x4 pe = *(const f32x4*)(posT + d * PSTR + pg * 16 + p_r0);
            *(f32x4*)&tile[l15][jl * 64 + pg * 16 + p_r0] = acc[pg] + pe;
        }
    }
    __syncthreads();

    const int ir = t >> 4;           // 0..15
    const int c  = t & 15;           // 0..15
    float* orow = out + (((size_t)(b * L_ + i0 + ir)) * L_ + j0) * P_;
    #pragma unroll
    for (int m = 0; m < 8; ++m) {
        const int f4 = m * 16 + c;
        const f32x4 v = *(const f32x4*)&tile[ir][f4 * 4];
        __builtin_nontemporal_store(v, (f32x4*)(orow + f4 * 4));
    }
}

extern "C" void kernel_launch(void* const* d_in, const int* in_sizes, int n_in,
                              void* d_out, int out_size, void* d_ws, size_t ws_size,
                              hipStream_t stream) {
    const float* x     = (const float*)d_in[0];
    const float* in_w  = (const float*)d_in[1];
    const float* in_b  = (const float*)d_in[2];
    const float* out_w = (const float*)d_in[3];
    const float* out_b = (const float*)d_in[4];
    const float* pos_w = (const float*)d_in[5];
    const float* pos_b = (const float*)d_in[6];
    float* out = (float*)d_out;

    __bf16* gb = (__bf16*)d_ws;                                   // 2 MB
    __bf16* hb = gb + (size_t)B_ * L_ * P_ * A_;                  // +32 KB

    k1_proj<<<dim3(512), 256, 0, stream>>>(x, in_w, in_b, out_w, gb, hb);
    k2_mfma<<<dim3(L_ / 8, L_ / 16, B_), 256, 0, stream>>>(gb, hb, out_b, pos_w, pos_b, out);
}

// Round 16
// 19.753 us; speedup vs baseline: 1.3866x; 1.1523x over previous
//
#include <hip/hip_runtime.h>

#define B_ 2
#define L_ 256
#define H_ 256
#define A_ 32
#define P_ 64
#define PSTR 76    // posT LDS row stride (floats)
#define TSTR 516   // out-tile LDS row stride (floats): 8*64 + 4
#define WPAD 264   // bf16 LDS row stride: 528B -> bank 4*row%32, <=2-way

typedef __bf16 bf16x8 __attribute__((ext_vector_type(8)));
typedef float  f32x4  __attribute__((ext_vector_type(4)));

// k1: 512 blocks = 64 row-groups (8 rows) x 8 p-octets.
// h-phase via MFMA: stage x rows + in_w as bf16 in LDS (padded), then
//   D[m=x-row][n=a] = sum_k x[m][k]*in_w[a][k] as 8 chained 16x16x32 MFMAs on
//   waves 0,1 (wave = a-half). DS traffic ~6x lower than R9's dual-LDS dots;
//   FMA work moves off the VALU. h = D + in_b, kept f32 in hl (g-phase input),
//   bf16 to hb (pe==0 only).
// g-phase: R9-verbatim broadcast form (measured-good).
__global__ __launch_bounds__(256) void k1_proj(
    const float* __restrict__ x,     // [B,L,H]
    const float* __restrict__ in_w,  // [A,H]
    const float* __restrict__ in_b,  // [A]
    const float* __restrict__ out_w, // [P, A*A]
    __bf16* __restrict__ gb,         // [B*L][P][A] bf16
    __bf16* __restrict__ hb)         // [B*L][A]   bf16
{
    __shared__ __align__(16) __bf16 xb[8][WPAD];    // x rows, bf16
    __shared__ __align__(16) __bf16 wsb[32][WPAD];  // in_w, bf16
    __shared__ float hl[8][36];                     // h rows, f32

    const int t = threadIdx.x;
    const int rowg = blockIdx.x >> 3;     // 0..63
    const int pe   = blockIdx.x & 7;      // p-octet
    const int r0 = rowg * 8;

    // stage x -> bf16 (thread: row = t>>5, 8 consecutive c)
    {
        const int row = t >> 5, c8 = t & 31;
        const float4* xp = (const float4*)(x + (size_t)(r0 + row) * H_ + c8 * 8);
        const float4 v0 = xp[0], v1 = xp[1];
        bf16x8 o;
        o[0] = (__bf16)v0.x; o[1] = (__bf16)v0.y; o[2] = (__bf16)v0.z; o[3] = (__bf16)v0.w;
        o[4] = (__bf16)v1.x; o[5] = (__bf16)v1.y; o[6] = (__bf16)v1.z; o[7] = (__bf16)v1.w;
        *(bf16x8*)&xb[row][c8 * 8] = o;
    }
    // stage in_w -> bf16 (1024 groups of 8 elems; 4 per thread)
    #pragma unroll
    for (int it = 0; it < 4; ++it) {
        const int gi = t + 256 * it;
        const int row = gi >> 5, c8 = gi & 31;
        const float4* wp = (const float4*)(in_w + (size_t)row * H_ + c8 * 8);
        const float4 v0 = wp[0], v1 = wp[1];
        bf16x8 o;
        o[0] = (__bf16)v0.x; o[1] = (__bf16)v0.y; o[2] = (__bf16)v0.z; o[3] = (__bf16)v0.w;
        o[4] = (__bf16)v1.x; o[5] = (__bf16)v1.y; o[6] = (__bf16)v1.z; o[7] = (__bf16)v1.w;
        *(bf16x8*)&wsb[row][c8 * 8] = o;
    }
    __syncthreads();

    // h via MFMA on waves 0,1 (wave wv covers a = wv*16 .. +15)
    const int lane = t & 63;
    const int wv = t >> 6;
    const int l15 = lane & 15;
    const int kq = lane >> 4;            // k-chunk in frags; D row group on output
    if (wv < 2) {
        f32x4 acc = {0.f, 0.f, 0.f, 0.f};
        #pragma unroll
        for (int ks = 0; ks < 8; ++ks) {
            // A: m-row = l15 (rows>=8 clamped -> duplicate, D rows 8..15 unused)
            const bf16x8 af = *(const bf16x8*)&xb[l15 & 7][ks * 32 + kq * 8];
            // B: n-col = a-local = l15
            const bf16x8 bf_ = *(const bf16x8*)&wsb[wv * 16 + l15][ks * 32 + kq * 8];
            acc = __builtin_amdgcn_mfma_f32_16x16x32_bf16(af, bf_, acc, 0, 0, 0);
        }
        if (kq < 2) {                    // D rows 0..7 are the real x-rows
            const int a = wv * 16 + l15;
            const float bias = in_b[a];
            #pragma unroll
            for (int reg = 0; reg < 4; ++reg) {
                const int row = kq * 4 + reg;
                const float hv = acc[reg] + bias;
                hl[row][a] = hv;
                if (pe == 0) hb[(size_t)(r0 + row) * A_ + a] = (__bf16)hv;
            }
        }
    }
    __syncthreads();

    // g-phase (R9-verbatim): thread owns p = pe*8 + (t>>5), a = t&31
    {
        const int p = pe * 8 + (t >> 5);
        const int a = t & 31;
        const float4* wrow = (const float4*)(out_w + (size_t)p * (A_ * A_) + a * A_);
        float4 w[8];
        #pragma unroll
        for (int m = 0; m < 8; ++m) w[m] = wrow[m];
        float sac[8];
        #pragma unroll
        for (int jj = 0; jj < 8; ++jj) {
            float s = 0.f;
            #pragma unroll
            for (int m = 0; m < 8; ++m) {
                const float4 h4 = *(const float4*)&hl[jj][m * 4];   // uniform -> broadcast
                s += w[m].x * h4.x + w[m].y * h4.y + w[m].z * h4.z + w[m].w * h4.w;
            }
            sac[jj] = s;
        }
        #pragma unroll
        for (int jj = 0; jj < 8; ++jj)
            gb[((size_t)(r0 + jj) * P_ + p) * A_ + a] = (__bf16)sac[jj];
    }
}

// k2: VERBATIM R9 measured-best. out[b,i,j,p] = sum_a g[j,a,p] h[i,a] via
// mfma(A=g, B=h): D[m=p][n=i]; 16i x 8j x 64p tiles; LDS-staged fused epilogue,
// linear NT readout.
__global__ __launch_bounds__(256) void k2_mfma(
    const __bf16* __restrict__ gb,   // [B*L][P][A]
    const __bf16* __restrict__ hb,   // [B*L][A]
    const float* __restrict__ out_b, // [P]
    const float* __restrict__ pos_w, // [P,17]
    const float* __restrict__ pos_b, // [P]
    float* __restrict__ out)         // [B,L,L,P]
{
    __shared__ float posT[17 * PSTR];
    __shared__ float tile[16][TSTR];
    const int t = threadIdx.x;

    for (int e = t; e < 17 * P_; e += 256) {
        const int d = e >> 6, p = e & 63;
        posT[d * PSTR + p] = pos_w[p * 17 + d] + pos_b[p] + out_b[p];
    }
    __syncthreads();

    const int lane = t & 63;
    const int w = t >> 6;            // wave 0..3
    const int j0 = blockIdx.x * 8;
    const int i0 = blockIdx.y * 16;
    const int b = blockIdx.z;

    const int l15 = lane & 15;
    const int hi = lane >> 4;        // 0..3
    const int i = i0 + l15;
    const int p_r0 = hi * 4;

    const bf16x8 hfrag = *(const bf16x8*)(hb + ((size_t)(b * L_ + i)) * A_ + hi * 8);
    const f32x4 zero = {0.f, 0.f, 0.f, 0.f};

    #pragma unroll
    for (int tj = 0; tj < 2; ++tj) {
        const int jl = w * 2 + tj;   // local j 0..7
        const int j = j0 + jl;
        const __bf16* gr = gb + ((size_t)(b * L_ + j)) * (P_ * A_);

        bf16x8 gfrag[4];
        #pragma unroll
        for (int pg = 0; pg < 4; ++pg)
            gfrag[pg] = *(const bf16x8*)(gr + (pg * 16 + l15) * A_ + hi * 8);

        f32x4 acc[4];
        #pragma unroll
        for (int pg = 0; pg < 4; ++pg)
            acc[pg] = __builtin_amdgcn_mfma_f32_16x16x32_bf16(gfrag[pg], hfrag, zero, 0, 0, 0);

        int d = i - j;
        d = d < -8 ? -8 : (d > 8 ? 8 : d);
        d += 8;

        #pragma unroll
        for (int pg = 0; pg < 4; ++pg) {
            const f32x4 pe = *(const f32x4*)(posT + d * PSTR + pg * 16 + p_r0);
            *(f32x4*)&tile[l15][jl * 64 + pg * 16 + p_r0] = acc[pg] + pe;
        }
    }
    __syncthreads();

    const int ir = t >> 4;           // 0..15
    const int c  = t & 15;           // 0..15
    float* orow = out + (((size_t)(b * L_ + i0 + ir)) * L_ + j0) * P_;
    #pragma unroll
    for (int m = 0; m < 8; ++m) {
        const int f4 = m * 16 + c;
        const f32x4 v = *(const f32x4*)&tile[ir][f4 * 4];
        __builtin_nontemporal_store(v, (f32x4*)(orow + f4 * 4));
    }
}

extern "C" void kernel_launch(void* const* d_in, const int* in_sizes, int n_in,
                              void* d_out, int out_size, void* d_ws, size_t ws_size,
                              hipStream_t stream) {
    const float* x     = (const float*)d_in[0];
    const float* in_w  = (const float*)d_in[1];
    const float* in_b  = (const float*)d_in[2];
    const float* out_w = (const float*)d_in[3];
    const float* out_b = (const float*)d_in[4];
    const float* pos_w = (const float*)d_in[5];
    const float* pos_b = (const float*)d_in[6];
    float* out = (float*)d_out;

    __bf16* gb = (__bf16*)d_ws;                                   // 2 MB
    __bf16* hb = gb + (size_t)B_ * L_ * P_ * A_;                  // +32 KB

    k1_proj<<<dim3(512), 256, 0, stream>>>(x, in_w, in_b, out_w, gb, hb);
    k2_mfma<<<dim3(L_ / 8, L_ / 16, B_), 256, 0, stream>>>(gb, hb, out_b, pos_w, pos_b, out);
}